// Round 4
// baseline (9701.125 us; speedup 1.0000x reference)
//
#include <hip/hip_runtime.h>

#define BT   4      // batch tile per block
#define HID  64
#define G4P  272    // padded gate-row stride (272 % 32 == 16 -> quad writes at worst 2-way = free)
#define SEQ  512
#define NOUT 12

typedef float f2 __attribute__((ext_vector_type(2)));

__device__ __forceinline__ float sigf(float x)  { return 1.f / (1.f + __expf(-x)); }
__device__ __forceinline__ float tanhf_fast(float x) { return 1.f - 2.f / (1.f + __expf(2.f * x)); }

// Sum v across the 4 lanes of each quad (lane&3 = ks) with DPP quad_perm butterflies.
// VALU-only on purpose: __shfl_xor lowers to ds_bpermute (LDS pipe), which is the
// bottleneck we are removing.
__device__ __forceinline__ float qsum(float v) {
    int a = __builtin_amdgcn_mov_dpp(__float_as_int(v), 0xB1, 0xF, 0xF, true); // quad_perm [1,0,3,2] (xor 1)
    v += __int_as_float(a);
    int b = __builtin_amdgcn_mov_dpp(__float_as_int(v), 0x4E, 0xF, 0xF, true); // quad_perm [2,3,0,1] (xor 2)
    v += __int_as_float(b);
    return v;
}

// Sharding: thread = (ks = tid&3, p = tid>>2). Owns gate rows {p, p+64, p+128, p+192}
// over K-slice [16*ks, 16*ks+16). Each ds_read_b128 of h feeds 12 packed FMAs
// (4 rows x up-to-3 matrices); per-thread LDS reads drop 128 -> 32 per step.
__global__ void __launch_bounds__(256) __attribute__((amdgpu_waves_per_eu(2, 2)))
lstm2_fused(
    const float* __restrict__ x,      // [B, SEQ, 1]
    const float* __restrict__ w_ih0,  // [256, 1]
    const float* __restrict__ w_hh0,  // [256, 64]
    const float* __restrict__ b_ih0,  // [256]
    const float* __restrict__ b_hh0,  // [256]
    const float* __restrict__ w_ih1,  // [256, 64]
    const float* __restrict__ w_hh1,  // [256, 64]
    const float* __restrict__ b_ih1,  // [256]
    const float* __restrict__ b_hh1,  // [256]
    const float* __restrict__ fc_w,   // [12, 64]
    const float* __restrict__ fc_b,   // [12]
    float* __restrict__ out)          // [B, 12]
{
    __shared__ float xs[BT][SEQ];    // 8 KB
    __shared__ float h0s[BT][HID];   // 1 KB
    __shared__ float h1s[BT][HID];   // 1 KB
    __shared__ float gs0[BT][G4P];   // gates layer0, step t+1 (padded stride)
    __shared__ float gs1[BT][G4P];   // gates layer1, step t

    const int tid = threadIdx.x;
    const int ks  = tid & 3;          // K-quarter (quad lane)
    const int p   = tid >> 2;         // row-group (0..63)
    const int j0  = ks * 16;          // K-slice start
    const int b0  = blockIdx.x * BT;

    // ---- loop-invariant weight slices: 96 f2 = 192 regs ----
    f2 w0p[4][8], wip[4][8], w1p[4][8];
    float wih0g[4], bias0[4], bias1[4];
#pragma unroll
    for (int r = 0; r < 4; ++r) {
        const int g = p + 64 * r;
        const float4* q0 = (const float4*)&w_hh0[g * HID + j0];
        const float4* qi = (const float4*)&w_ih1[g * HID + j0];
        const float4* q1 = (const float4*)&w_hh1[g * HID + j0];
#pragma unroll
        for (int j = 0; j < 4; ++j) {
            float4 a = q0[j]; w0p[r][2*j] = f2{a.x, a.y}; w0p[r][2*j+1] = f2{a.z, a.w};
            float4 b = qi[j]; wip[r][2*j] = f2{b.x, b.y}; wip[r][2*j+1] = f2{b.z, b.w};
            float4 c = q1[j]; w1p[r][2*j] = f2{c.x, c.y}; w1p[r][2*j+1] = f2{c.z, c.w};
        }
        wih0g[r] = w_ih0[g];
        bias0[r] = b_ih0[g] + b_hh0[g];
        bias1[r] = b_ih1[g] + b_hh1[g];
    }

    // ---- stage this block's x tile into LDS; zero-init h ----
    for (int i = tid; i < BT * SEQ; i += 256) {
        int b = i >> 9, t = i & (SEQ - 1);
        xs[b][t] = x[(size_t)(b0 + b) * SEQ + t];
    }
    for (int i = tid; i < BT * HID; i += 256) {
        ((float*)h0s)[i] = 0.f;
        ((float*)h1s)[i] = 0.f;
    }
    const int eb = tid >> 6;     // batch   (elementwise phase)
    const int ej = tid & 63;     // hidden  (elementwise phase)
    float c0 = 0.f, c1 = 0.f;
    __syncthreads();

    // ===== prologue: gates0(0) = bias0 + x[0]*w_ih0  (h0 init = 0) =====
#pragma unroll
    for (int r = 0; r < 4; ++r)
        gs0[ks][p + 64 * r] = fmaf(xs[ks][0], wih0g[r], bias0[r]);
    __syncthreads();
    {   // ew0 -> h0(0), c0(0)
        float ig = sigf(gs0[eb][ej]);
        float fg = sigf(gs0[eb][64 + ej]);
        float gg = tanhf_fast(gs0[eb][128 + ej]);
        float og = sigf(gs0[eb][192 + ej]);
        c0 = fg * c0 + ig * gg;
        h0s[eb][ej] = og * tanhf_fast(c0);
    }
    __syncthreads();

    for (int t = 0; t < SEQ; ++t) {
        const int tx = (t + 1 < SEQ) ? (t + 1) : (SEQ - 1);  // clamped dummy at t=511

        // S0[b][r]: full K-sum of h0(t) . w_hh0[row r]      (gates0(t+1), pre-bias)
        // S1[b][r]: full K-sum of h0.w_ih1 + h1.w_hh1       (gates1(t),   pre-bias)
        float S0[BT][4], S1[BT][4];
#pragma unroll
        for (int b = 0; b < BT; ++b) {
            f2 A0[4] = {f2{0,0}, f2{0,0}, f2{0,0}, f2{0,0}};
            f2 A1[4] = {f2{0,0}, f2{0,0}, f2{0,0}, f2{0,0}};
#pragma unroll
            for (int i = 0; i < 16; i += 4) {
                float4 h0v = *(const float4*)&h0s[b][j0 + i];   // 4-addr broadcast, 2-way max
                float4 h1v = *(const float4*)&h1s[b][j0 + i];
                f2 h0a = f2{h0v.x, h0v.y}, h0b = f2{h0v.z, h0v.w};
                f2 h1a = f2{h1v.x, h1v.y}, h1b = f2{h1v.z, h1v.w};
                const int k = i >> 1;
#pragma unroll
                for (int r = 0; r < 4; ++r) {
                    A0[r] = __builtin_elementwise_fma(h0a, w0p[r][k],     A0[r]);
                    A0[r] = __builtin_elementwise_fma(h0b, w0p[r][k + 1], A0[r]);
                    A1[r] = __builtin_elementwise_fma(h0a, wip[r][k],     A1[r]);
                    A1[r] = __builtin_elementwise_fma(h0b, wip[r][k + 1], A1[r]);
                    A1[r] = __builtin_elementwise_fma(h1a, w1p[r][k],     A1[r]);
                    A1[r] = __builtin_elementwise_fma(h1b, w1p[r][k + 1], A1[r]);
                }
            }
#pragma unroll
            for (int r = 0; r < 4; ++r) {
                S0[b][r] = qsum(A0[r][0] + A0[r][1]);   // all 4 quad lanes end with full sum
                S1[b][r] = qsum(A1[r][0] + A1[r][1]);
            }
        }

        // ===== distribute: quad lane ks writes batch b = ks =====
        const float xt = xs[ks][tx];
#pragma unroll
        for (int r = 0; r < 4; ++r) {
            float g0v = (ks == 0) ? S0[0][r] : (ks == 1) ? S0[1][r] : (ks == 2) ? S0[2][r] : S0[3][r];
            float g1v = (ks == 0) ? S1[0][r] : (ks == 1) ? S1[1][r] : (ks == 2) ? S1[2][r] : S1[3][r];
            gs0[ks][p + 64 * r] = fmaf(xt, wih0g[r], bias0[r]) + g0v;
            gs1[ks][p + 64 * r] = bias1[r] + g1v;
        }
        __syncthreads();

        // ===== merged elementwise phase: ew0(t+1) and ew1(t) =====
        {
            float ig = sigf(gs0[eb][ej]);
            float fg = sigf(gs0[eb][64 + ej]);
            float gg = tanhf_fast(gs0[eb][128 + ej]);
            float og = sigf(gs0[eb][192 + ej]);
            c0 = fg * c0 + ig * gg;
            h0s[eb][ej] = og * tanhf_fast(c0);

            float ig1 = sigf(gs1[eb][ej]);
            float fg1 = sigf(gs1[eb][64 + ej]);
            float gg1 = tanhf_fast(gs1[eb][128 + ej]);
            float og1 = sigf(gs1[eb][192 + ej]);
            c1 = fg1 * c1 + ig1 * gg1;
            h1s[eb][ej] = og1 * tanhf_fast(c1);
        }
        __syncthreads();
    }

    // ===== final projection: out[b][o] = fc_b[o] + h1(511) . fc_w[o] =====
    if (tid < BT * NOUT) {
        int b = tid / NOUT, o = tid % NOUT;
        float acc = fc_b[o];
#pragma unroll
        for (int j = 0; j < HID; ++j)
            acc = fmaf(fc_w[o * HID + j], h1s[b][j], acc);
        out[(size_t)(b0 + b) * NOUT + o] = acc;
    }
}

extern "C" void kernel_launch(void* const* d_in, const int* in_sizes, int n_in,
                              void* d_out, int out_size, void* d_ws, size_t ws_size,
                              hipStream_t stream) {
    const float* x     = (const float*)d_in[0];
    const float* w_ih0 = (const float*)d_in[1];
    const float* w_hh0 = (const float*)d_in[2];
    const float* b_ih0 = (const float*)d_in[3];
    const float* b_hh0 = (const float*)d_in[4];
    const float* w_ih1 = (const float*)d_in[5];
    const float* w_hh1 = (const float*)d_in[6];
    const float* b_ih1 = (const float*)d_in[7];
    const float* b_hh1 = (const float*)d_in[8];
    const float* fc_w  = (const float*)d_in[9];
    const float* fc_b  = (const float*)d_in[10];

    const int B = in_sizes[0] / SEQ;          // 2048
    dim3 grid(B / BT);                        // 512 blocks -> 2 blocks/CU
    lstm2_fused<<<grid, 256, 0, stream>>>(x, w_ih0, w_hh0, b_ih0, b_hh0,
                                          w_ih1, w_hh1, b_ih1, b_hh1,
                                          fc_w, fc_b, (float*)d_out);
}

// Round 5
// 1662.634 us; speedup vs baseline: 5.8348x; 5.8348x over previous
//
#include <hip/hip_runtime.h>

#define BT   4      // batch tile per block
#define HID  64
#define G4   256    // 4*HID
#define SEQ  512
#define NOUT 12

typedef float f2 __attribute__((ext_vector_type(2)));

__device__ __forceinline__ float sigf(float x)  { return 1.f / (1.f + __expf(-x)); }
__device__ __forceinline__ float tanhf_fast(float x) { return 1.f - 2.f / (1.f + __expf(2.f * x)); }

// Pair-sum: add the partner lane of each even/odd pair (quad_perm [1,0,3,2] = xor 1).
// VALU-only on purpose: __shfl_xor lowers to ds_bpermute, which rides the LDS pipe
// we are offloading.
__device__ __forceinline__ float psum(float v) {
    int a = __builtin_amdgcn_mov_dpp(__float_as_int(v), 0xB1, 0xF, 0xF, true);
    return v + __int_as_float(a);
}

// Sharding: thread = (ks = tid&1, p = tid>>1). Owns gate rows {p, p+128} over
// K-slice [32*ks, 32*ks+32). 192 weight floats/thread (same as the proven no-spill
// profile); per-thread LDS b128 reads drop 128 -> 64 per step; each read feeds
// 6-12 packed FMAs. Batch-major: sums retired to LDS immediately, nothing carried.
__global__ void __launch_bounds__(256) __attribute__((amdgpu_waves_per_eu(2, 2)))
lstm2_fused(
    const float* __restrict__ x,      // [B, SEQ, 1]
    const float* __restrict__ w_ih0,  // [256, 1]
    const float* __restrict__ w_hh0,  // [256, 64]
    const float* __restrict__ b_ih0,  // [256]
    const float* __restrict__ b_hh0,  // [256]
    const float* __restrict__ w_ih1,  // [256, 64]
    const float* __restrict__ w_hh1,  // [256, 64]
    const float* __restrict__ b_ih1,  // [256]
    const float* __restrict__ b_hh1,  // [256]
    const float* __restrict__ fc_w,   // [12, 64]
    const float* __restrict__ fc_b,   // [12]
    float* __restrict__ out)          // [B, 12]
{
    __shared__ float xs[BT][SEQ];    // 8 KB
    __shared__ float h0s[BT][HID];   // 1 KB
    __shared__ float h1s[BT][HID];   // 1 KB
    __shared__ float gs0[BT][G4];    // 4 KB  gates layer0, step t+1
    __shared__ float gs1[BT][G4];    // 4 KB  gates layer1, step t

    const int tid = threadIdx.x;
    const int ks  = tid & 1;          // K-half (pair lane)
    const int p   = tid >> 1;         // row index (0..127); rows {p, p+128}
    const int j0  = ks * 32;          // K-slice start
    const int b0  = blockIdx.x * BT;

    // ---- loop-invariant weight slices: 96 f2 = 192 regs (VGPR+AGPR) ----
    f2 w0p[2][16], wip[2][16], w1p[2][16];
    float wih0g[2], bias0v[2], bias1v[2];
#pragma unroll
    for (int r = 0; r < 2; ++r) {
        const int g = p + 128 * r;
        const float4* q0 = (const float4*)&w_hh0[g * HID + j0];
        const float4* qi = (const float4*)&w_ih1[g * HID + j0];
        const float4* q1 = (const float4*)&w_hh1[g * HID + j0];
#pragma unroll
        for (int j = 0; j < 8; ++j) {
            float4 a = q0[j]; w0p[r][2*j] = f2{a.x, a.y}; w0p[r][2*j+1] = f2{a.z, a.w};
            float4 b = qi[j]; wip[r][2*j] = f2{b.x, b.y}; wip[r][2*j+1] = f2{b.z, b.w};
            float4 c = q1[j]; w1p[r][2*j] = f2{c.x, c.y}; w1p[r][2*j+1] = f2{c.z, c.w};
        }
        wih0g[r]  = w_ih0[g];
        bias0v[r] = b_ih0[g] + b_hh0[g];
        bias1v[r] = b_ih1[g] + b_hh1[g];
    }

    // ---- stage this block's x tile into LDS; zero-init h ----
    for (int i = tid; i < BT * SEQ; i += 256) {
        int b = i >> 9, t = i & (SEQ - 1);
        xs[b][t] = x[(size_t)(b0 + b) * SEQ + t];
    }
    for (int i = tid; i < BT * HID; i += 256) {
        ((float*)h0s)[i] = 0.f;
        ((float*)h1s)[i] = 0.f;
    }
    const int eb = tid >> 6;     // batch   (elementwise phase)
    const int ej = tid & 63;     // hidden  (elementwise phase)
    float c0 = 0.f, c1 = 0.f;
    __syncthreads();

    // ===== prologue: gates0(0) = bias0 + x[0]*w_ih0  (h0 init = 0) =====
#pragma unroll
    for (int b = 0; b < BT; ++b) {
        if (ks == (b & 1)) {
            gs0[b][p]       = fmaf(xs[b][0], wih0g[0], bias0v[0]);
            gs0[b][p + 128] = fmaf(xs[b][0], wih0g[1], bias0v[1]);
        }
    }
    __syncthreads();
    {   // ew0 -> h0(0), c0(0)
        float ig = sigf(gs0[eb][ej]);
        float fg = sigf(gs0[eb][64 + ej]);
        float gg = tanhf_fast(gs0[eb][128 + ej]);
        float og = sigf(gs0[eb][192 + ej]);
        c0 = fg * c0 + ig * gg;
        h0s[eb][ej] = og * tanhf_fast(c0);
    }
    __syncthreads();

    for (int t = 0; t < SEQ; ++t) {
        const int tx = (t + 1 < SEQ) ? (t + 1) : (SEQ - 1);  // clamped dummy at t=511

        // gates0(t+1)[rows p, p+128] = bias0 + x[t+1]*w_ih0 + h0(t) . w_hh0
        // gates1(t)  [rows p, p+128] = bias1 + h0(t) . w_ih1 + h1(t-1) . w_hh1
#pragma unroll
        for (int b = 0; b < BT; ++b) {
            f2 A00 = f2{0.f, 0.f};   // layer0 row p
            f2 A01 = f2{0.f, 0.f};   // layer0 row p+128
            f2 A10 = f2{0.f, 0.f};   // layer1 row p
            f2 A11 = f2{0.f, 0.f};   // layer1 row p+128
#pragma unroll
            for (int i = 0; i < 32; i += 4) {
                float4 h0v = *(const float4*)&h0s[b][j0 + i];   // 2 addrs/wave: free 2-way
                float4 h1v = *(const float4*)&h1s[b][j0 + i];
                f2 h0a = f2{h0v.x, h0v.y}, h0b = f2{h0v.z, h0v.w};
                f2 h1a = f2{h1v.x, h1v.y}, h1b = f2{h1v.z, h1v.w};
                const int k = i >> 1;
                A00 = __builtin_elementwise_fma(h0a, w0p[0][k],     A00);
                A00 = __builtin_elementwise_fma(h0b, w0p[0][k + 1], A00);
                A01 = __builtin_elementwise_fma(h0a, w0p[1][k],     A01);
                A01 = __builtin_elementwise_fma(h0b, w0p[1][k + 1], A01);
                A10 = __builtin_elementwise_fma(h0a, wip[0][k],     A10);
                A10 = __builtin_elementwise_fma(h0b, wip[0][k + 1], A10);
                A10 = __builtin_elementwise_fma(h1a, w1p[0][k],     A10);
                A10 = __builtin_elementwise_fma(h1b, w1p[0][k + 1], A10);
                A11 = __builtin_elementwise_fma(h0a, wip[1][k],     A11);
                A11 = __builtin_elementwise_fma(h0b, wip[1][k + 1], A11);
                A11 = __builtin_elementwise_fma(h1a, w1p[1][k],     A11);
                A11 = __builtin_elementwise_fma(h1b, w1p[1][k + 1], A11);
            }
            // complete K-sum across the lane pair; retire immediately (nothing carried)
            float s00 = psum(A00[0] + A00[1]);
            float s01 = psum(A01[0] + A01[1]);
            float s10 = psum(A10[0] + A10[1]);
            float s11 = psum(A11[0] + A11[1]);
            if (ks == (b & 1)) {
                gs0[b][p]       = fmaf(xs[b][tx], wih0g[0], bias0v[0]) + s00;
                gs0[b][p + 128] = fmaf(xs[b][tx], wih0g[1], bias0v[1]) + s01;
                gs1[b][p]       = bias1v[0] + s10;
                gs1[b][p + 128] = bias1v[1] + s11;
            }
        }
        __syncthreads();

        // ===== merged elementwise phase: ew0(t+1) and ew1(t) =====
        {
            float ig = sigf(gs0[eb][ej]);
            float fg = sigf(gs0[eb][64 + ej]);
            float gg = tanhf_fast(gs0[eb][128 + ej]);
            float og = sigf(gs0[eb][192 + ej]);
            c0 = fg * c0 + ig * gg;
            h0s[eb][ej] = og * tanhf_fast(c0);

            float ig1 = sigf(gs1[eb][ej]);
            float fg1 = sigf(gs1[eb][64 + ej]);
            float gg1 = tanhf_fast(gs1[eb][128 + ej]);
            float og1 = sigf(gs1[eb][192 + ej]);
            c1 = fg1 * c1 + ig1 * gg1;
            h1s[eb][ej] = og1 * tanhf_fast(c1);
        }
        __syncthreads();
    }

    // ===== final projection: out[b][o] = fc_b[o] + h1(511) . fc_w[o] =====
    if (tid < BT * NOUT) {
        int b = tid / NOUT, o = tid % NOUT;
        float acc = fc_b[o];
#pragma unroll
        for (int j = 0; j < HID; ++j)
            acc = fmaf(fc_w[o * HID + j], h1s[b][j], acc);
        out[(size_t)(b0 + b) * NOUT + o] = acc;
    }
}

extern "C" void kernel_launch(void* const* d_in, const int* in_sizes, int n_in,
                              void* d_out, int out_size, void* d_ws, size_t ws_size,
                              hipStream_t stream) {
    const float* x     = (const float*)d_in[0];
    const float* w_ih0 = (const float*)d_in[1];
    const float* w_hh0 = (const float*)d_in[2];
    const float* b_ih0 = (const float*)d_in[3];
    const float* b_hh0 = (const float*)d_in[4];
    const float* w_ih1 = (const float*)d_in[5];
    const float* w_hh1 = (const float*)d_in[6];
    const float* b_ih1 = (const float*)d_in[7];
    const float* b_hh1 = (const float*)d_in[8];
    const float* fc_w  = (const float*)d_in[9];
    const float* fc_b  = (const float*)d_in[10];

    const int B = in_sizes[0] / SEQ;          // 2048
    dim3 grid(B / BT);                        // 512 blocks -> 2 blocks/CU
    lstm2_fused<<<grid, 256, 0, stream>>>(x, w_ih0, w_hh0, b_ih0, b_hh0,
                                          w_ih1, w_hh1, b_ih1, b_hh1,
                                          fc_w, fc_b, (float*)d_out);
}

// Round 6
// 1580.551 us; speedup vs baseline: 6.1378x; 1.0519x over previous
//
#include <hip/hip_runtime.h>

#define BT   4      // batch tile per block
#define HID  64
#define HP   72     // padded h row stride (max 2-way bank aliasing = free)
#define SEQ  512
#define NOUT 12

typedef float f2 __attribute__((ext_vector_type(2)));

__device__ __forceinline__ float sigf(float x)  { return 1.f / (1.f + __expf(-x)); }
__device__ __forceinline__ float tanhf_fast(float x) { return 1.f - 2.f / (1.f + __expf(2.f * x)); }

// Full sum across the 4 lanes of each quad (lane&3 = ks): two DPP quad_perm
// butterflies (xor 1, xor 2). VALU-only — __shfl_xor would ride the LDS pipe.
__device__ __forceinline__ float qsum4(float v) {
    int a = __builtin_amdgcn_mov_dpp(__float_as_int(v), 0xB1, 0xF, 0xF, true); // [1,0,3,2]
    v += __int_as_float(a);
    int b = __builtin_amdgcn_mov_dpp(__float_as_int(v), 0x4E, 0xF, 0xF, true); // [2,3,0,1]
    v += __int_as_float(b);
    return v;
}

// Sharding: thread = (ks = tid&3, p = tid>>2). Owns the FOUR GATE ROWS of hidden
// unit p: {p, p+64, p+128, p+192}, over K-slice [16*ks, 16*ks+16).
// After the quad butterfly this thread has all of (i,f,g,o) for (batch, unit p),
// so the LSTM elementwise fuses in-thread: no gate arrays in LDS, 1 barrier/step.
// h0s/h1s double-buffered by t-parity to remove the write-after-read hazard.
__global__ void __launch_bounds__(256) __attribute__((amdgpu_waves_per_eu(2, 2)))
lstm2_fused(
    const float* __restrict__ x,      // [B, SEQ, 1]
    const float* __restrict__ w_ih0,  // [256, 1]
    const float* __restrict__ w_hh0,  // [256, 64]
    const float* __restrict__ b_ih0,  // [256]
    const float* __restrict__ b_hh0,  // [256]
    const float* __restrict__ w_ih1,  // [256, 64]
    const float* __restrict__ w_hh1,  // [256, 64]
    const float* __restrict__ b_ih1,  // [256]
    const float* __restrict__ b_hh1,  // [256]
    const float* __restrict__ fc_w,   // [12, 64]
    const float* __restrict__ fc_b,   // [12]
    float* __restrict__ out)          // [B, 12]
{
    __shared__ float xs[BT][SEQ];     // 8 KB
    __shared__ float h0s[2][BT][HP];  // 2.25 KB (double-buffered)
    __shared__ float h1s[2][BT][HP];  // 2.25 KB

    const int tid = threadIdx.x;
    const int ks  = tid & 3;          // K-quarter (quad lane)
    const int p   = tid >> 2;         // hidden unit owned (0..63)
    const int j0  = ks * 16;          // K-slice start
    const int b0  = blockIdx.x * BT;

    // ---- loop-invariant weight slices: 96 f2 = 192 regs ----
    f2 w0p[4][8], wip[4][8], w1p[4][8];
    float wih0g[4], bias0v[4], bias1v[4];
#pragma unroll
    for (int r = 0; r < 4; ++r) {
        const int g = p + 64 * r;     // gate row r (i,f,g,o) of unit p
        const float4* q0 = (const float4*)&w_hh0[g * HID + j0];
        const float4* qi = (const float4*)&w_ih1[g * HID + j0];
        const float4* q1 = (const float4*)&w_hh1[g * HID + j0];
#pragma unroll
        for (int j = 0; j < 4; ++j) {
            float4 a = q0[j]; w0p[r][2*j] = f2{a.x, a.y}; w0p[r][2*j+1] = f2{a.z, a.w};
            float4 b = qi[j]; wip[r][2*j] = f2{b.x, b.y}; wip[r][2*j+1] = f2{b.z, b.w};
            float4 c = q1[j]; w1p[r][2*j] = f2{c.x, c.y}; w1p[r][2*j+1] = f2{c.z, c.w};
        }
        wih0g[r]  = w_ih0[g];
        bias0v[r] = b_ih0[g] + b_hh0[g];
        bias1v[r] = b_ih1[g] + b_hh1[g];
    }

    // ---- stage x; zero both h buffers ----
    for (int i = tid; i < BT * SEQ; i += 256) {
        int b = i >> 9, t = i & (SEQ - 1);
        xs[b][t] = x[(size_t)(b0 + b) * SEQ + t];
    }
    for (int i = tid; i < 2 * BT * HP; i += 256) {
        ((float*)h0s)[i] = 0.f;
        ((float*)h1s)[i] = 0.f;
    }
    float c0 = 0.f, c1 = 0.f;
    __syncthreads();

    // ===== prologue: h0(0) for (batch ks, unit p); h1(-1)=0 already =====
    {
        float ig = sigf(fmaf(xs[ks][0], wih0g[0], bias0v[0]));
        float fg = sigf(fmaf(xs[ks][0], wih0g[1], bias0v[1]));
        float gg = tanhf_fast(fmaf(xs[ks][0], wih0g[2], bias0v[2]));
        float og = sigf(fmaf(xs[ks][0], wih0g[3], bias0v[3]));
        c0 = ig * gg;                                  // f*c_prev = 0
        h0s[0][ks][p] = og * tanhf_fast(c0);
    }
    __syncthreads();

    for (int t = 0; t < SEQ; ++t) {
        const int cur = t & 1, nxt = cur ^ 1;
        const int tx  = (t + 1 < SEQ) ? (t + 1) : (SEQ - 1);  // clamped dummy at t=511

        // raw dot sums for THIS lane's batch (b = ks): layer0 rows r, layer1 rows r
        float g0sv[4] = {0.f, 0.f, 0.f, 0.f};
        float g1sv[4] = {0.f, 0.f, 0.f, 0.f};

#pragma unroll
        for (int b = 0; b < BT; ++b) {
            f2 A0[4] = {f2{0,0}, f2{0,0}, f2{0,0}, f2{0,0}};
            f2 A1[4] = {f2{0,0}, f2{0,0}, f2{0,0}, f2{0,0}};
#pragma unroll
            for (int i = 0; i < 16; i += 4) {
                float4 h0v = *(const float4*)&h0s[cur][b][j0 + i];  // read once, feeds l0+l1
                float4 h1v = *(const float4*)&h1s[cur][b][j0 + i];
                f2 h0a = f2{h0v.x, h0v.y}, h0b = f2{h0v.z, h0v.w};
                f2 h1a = f2{h1v.x, h1v.y}, h1b = f2{h1v.z, h1v.w};
                const int k = i >> 1;
#pragma unroll
                for (int r = 0; r < 4; ++r) {
                    A0[r] = __builtin_elementwise_fma(h0a, w0p[r][k],     A0[r]);
                    A0[r] = __builtin_elementwise_fma(h0b, w0p[r][k + 1], A0[r]);
                    A1[r] = __builtin_elementwise_fma(h0a, wip[r][k],     A1[r]);
                    A1[r] = __builtin_elementwise_fma(h0b, wip[r][k + 1], A1[r]);
                    A1[r] = __builtin_elementwise_fma(h1a, w1p[r][k],     A1[r]);
                    A1[r] = __builtin_elementwise_fma(h1b, w1p[r][k + 1], A1[r]);
                }
            }
            const bool mine = (ks == b);
#pragma unroll
            for (int r = 0; r < 4; ++r) {
                float s0 = qsum4(A0[r][0] + A0[r][1]);   // full K-sum in all quad lanes
                float s1 = qsum4(A1[r][0] + A1[r][1]);
                g0sv[r] = mine ? s0 : g0sv[r];           // keep only my batch's sums
                g1sv[r] = mine ? s1 : g1sv[r];
            }
        }

        // ===== fused elementwise (all lanes active): batch ks, unit p =====
        {
            const float xt = xs[ks][tx];
            float ig = sigf(g0sv[0] + fmaf(xt, wih0g[0], bias0v[0]));
            float fg = sigf(g0sv[1] + fmaf(xt, wih0g[1], bias0v[1]));
            float gg = tanhf_fast(g0sv[2] + fmaf(xt, wih0g[2], bias0v[2]));
            float og = sigf(g0sv[3] + fmaf(xt, wih0g[3], bias0v[3]));
            c0 = fg * c0 + ig * gg;
            h0s[nxt][ks][p] = og * tanhf_fast(c0);       // h0(t+1)

            float ig1 = sigf(g1sv[0] + bias1v[0]);
            float fg1 = sigf(g1sv[1] + bias1v[1]);
            float gg1 = tanhf_fast(g1sv[2] + bias1v[2]);
            float og1 = sigf(g1sv[3] + bias1v[3]);
            c1 = fg1 * c1 + ig1 * gg1;
            h1s[nxt][ks][p] = og1 * tanhf_fast(c1);      // h1(t)
        }
        __syncthreads();    // single barrier per step
    }

    // ===== final projection: h1(511) lives in buffer 0 =====
    if (tid < BT * NOUT) {
        int b = tid / NOUT, o = tid % NOUT;
        float acc = fc_b[o];
#pragma unroll
        for (int j = 0; j < HID; ++j)
            acc = fmaf(fc_w[o * HID + j], h1s[0][b][j], acc);
        out[(size_t)(b0 + b) * NOUT + o] = acc;
    }
}

extern "C" void kernel_launch(void* const* d_in, const int* in_sizes, int n_in,
                              void* d_out, int out_size, void* d_ws, size_t ws_size,
                              hipStream_t stream) {
    const float* x     = (const float*)d_in[0];
    const float* w_ih0 = (const float*)d_in[1];
    const float* w_hh0 = (const float*)d_in[2];
    const float* b_ih0 = (const float*)d_in[3];
    const float* b_hh0 = (const float*)d_in[4];
    const float* w_ih1 = (const float*)d_in[5];
    const float* w_hh1 = (const float*)d_in[6];
    const float* b_ih1 = (const float*)d_in[7];
    const float* b_hh1 = (const float*)d_in[8];
    const float* fc_w  = (const float*)d_in[9];
    const float* fc_b  = (const float*)d_in[10];

    const int B = in_sizes[0] / SEQ;          // 2048
    dim3 grid(B / BT);                        // 512 blocks -> 2 blocks/CU
    lstm2_fused<<<grid, 256, 0, stream>>>(x, w_ih0, w_hh0, b_ih0, b_hh0,
                                          w_ih1, w_hh1, b_ih1, b_hh1,
                                          fc_w, fc_b, (float*)d_out);
}

// Round 7
// 1036.400 us; speedup vs baseline: 9.3604x; 1.5250x over previous
//
#include <hip/hip_runtime.h>

#define BT    8      // batch tile per block
#define HID   64
#define SEQ   512
#define NOUT  12
#define XST   513    // padded x row stride (floats)
#define KP    36     // frag row stride in dwords (16B-aligned, spreads banks)

typedef float  f32x4  __attribute__((ext_vector_type(4)));
typedef short  bf16x8 __attribute__((ext_vector_type(8)));
typedef unsigned int u32;

union FW { bf16x8 v; u32 w[4]; uint4 q; };

__device__ __forceinline__ float sigf(float x)       { return 1.f / (1.f + __expf(-x)); }
__device__ __forceinline__ float tanhf_fast(float x) { return 1.f - 2.f / (1.f + __expf(2.f * x)); }
__device__ __forceinline__ u32  packbf2(float a, float b) {
    return (__float_as_uint(a) >> 16) | (__float_as_uint(b) & 0xFFFF0000u);
}
__device__ __forceinline__ float trunc_bf(float a) {
    return __uint_as_float(__float_as_uint(a) & 0xFFFF0000u);
}
// Split 8 f32 into hi/lo bf16x8 fragments (element j <-> k-offset j, ascending).
__device__ __forceinline__ void split8(const float f[8], bf16x8& hi, bf16x8& lo) {
    FW H, L;
#pragma unroll
    for (int i = 0; i < 4; ++i) {
        float a = f[2*i], b = f[2*i+1];
        H.w[i] = packbf2(a, b);
        L.w[i] = packbf2(a - trunc_bf(a), b - trunc_bf(b));
    }
    hi = H.v; lo = L.v;
}

// MFMA-based 2-layer LSTM. 8 waves: 0-3 layer0 (W_hh0, K=64), 4-7 layer1
// ([W_ih1|W_hh1], K=128). Weights as split-bf16 A-fragments (loop-invariant,
// AGPR-resident, read by MFMA directly). h exchanged via LDS as PRE-PACKED
// bf16 hi/lo fragment dwords -> B-frag build is one uint4 read per k-tile.
// Gate tile set {64g+16w} gives each lane all four gates of its units ->
// in-register elementwise, c-state in registers, 1 barrier/step.
__global__ void __launch_bounds__(512) __attribute__((amdgpu_waves_per_eu(2, 2)))
lstm2_fused(
    const float* __restrict__ x,      // [B, SEQ, 1]
    const float* __restrict__ w_ih0,  // [256, 1]
    const float* __restrict__ w_hh0,  // [256, 64]
    const float* __restrict__ b_ih0,  // [256]
    const float* __restrict__ b_hh0,  // [256]
    const float* __restrict__ w_ih1,  // [256, 64]
    const float* __restrict__ w_hh1,  // [256, 64]
    const float* __restrict__ b_ih1,  // [256]
    const float* __restrict__ b_hh1,  // [256]
    const float* __restrict__ fc_w,   // [12, 64]
    const float* __restrict__ fc_b,   // [12]
    float* __restrict__ out)          // [B, 12]
{
    __shared__ float xs[BT][XST];          // 16.4 KB
    __shared__ u32   h0f[2][2][16][KP];    // 18 KB  [dbuf][hi/lo][n][k2]
    __shared__ u32   h1f[2][2][16][KP];    // 18 KB
    __shared__ float h1last[BT][72];       // 2.3 KB

    const int tid = threadIdx.x;
    const int wid = tid >> 6;
    const int l   = tid & 63;
    const int n   = l & 15;      // MFMA row/col lane index (batch col; A-row)
    const int qg  = l >> 4;      // lane k-group (0..3)
    const int b0  = blockIdx.x * BT;

    // ---- stage x; zero frag buffers (rows n=8..15 stay zero forever) ----
    for (int i = tid; i < BT * SEQ; i += 512) {
        int b = i >> 9, t = i & (SEQ - 1);
        xs[b][t] = x[(size_t)(b0 + b) * SEQ + t];
    }
    for (int i = tid; i < 2 * 2 * 16 * KP; i += 512) {
        ((u32*)h0f)[i] = 0u;
        ((u32*)h1f)[i] = 0u;
    }
    __syncthreads();

    if (wid < 4) {
        // ================= layer 0 waves =================
        const int w = wid;
        bf16x8 Ah[4][2], Al[4][2];           // 4 gate-tiles x 2 k-tiles
#pragma unroll
        for (int g = 0; g < 4; ++g) {
            const int row = 64 * g + 16 * w + n;   // A-row this lane supplies
#pragma unroll
            for (int kt = 0; kt < 2; ++kt) {
                float f[8];
                *(float4*)&f[0] = *(const float4*)&w_hh0[row * HID + 32 * kt + 8 * qg];
                *(float4*)&f[4] = *(const float4*)&w_hh0[row * HID + 32 * kt + 8 * qg + 4];
                split8(f, Ah[g][kt], Al[g][kt]);
            }
        }
        float wih[4][4], bia[4][4];
#pragma unroll
        for (int g = 0; g < 4; ++g)
#pragma unroll
            for (int r = 0; r < 4; ++r) {
                int row = 64 * g + 16 * w + 4 * qg + r;   // D-row this lane owns
                wih[g][r] = w_ih0[row];
                bia[g][r] = b_ih0[row] + b_hh0[row];
            }
        const int  bb  = n & 7;           // in-bounds batch for x reads
        const bool act = (n < BT);        // lane owns a real batch
        const int  k2  = (16 * w + 4 * qg) >> 1;   // frag dword base for owned units
        float c0[4] = {0.f, 0.f, 0.f, 0.f};

        // prologue: h0(0) from x(0) only (h0(-1)=0)
        {
            float xv = xs[bb][0];
            float h[4];
#pragma unroll
            for (int r = 0; r < 4; ++r) {
                float ig = sigf(fmaf(xv, wih[0][r], bia[0][r]));
                float fg = sigf(fmaf(xv, wih[1][r], bia[1][r]));
                float gg = tanhf_fast(fmaf(xv, wih[2][r], bia[2][r]));
                float og = sigf(fmaf(xv, wih[3][r], bia[3][r]));
                (void)fg;
                c0[r] = ig * gg;
                h[r]  = og * tanhf_fast(c0[r]);
            }
            if (act) {
                uint2 hw = {packbf2(h[0], h[1]), packbf2(h[2], h[3])};
                uint2 lw = {packbf2(h[0] - trunc_bf(h[0]), h[1] - trunc_bf(h[1])),
                            packbf2(h[2] - trunc_bf(h[2]), h[3] - trunc_bf(h[3]))};
                *(uint2*)&h0f[0][0][n][k2] = hw;
                *(uint2*)&h0f[0][1][n][k2] = lw;
            }
        }
        __syncthreads();

        for (int t = 0; t < SEQ; ++t) {
            const int cur = t & 1, nxt = cur ^ 1;
            const int tx  = (t + 1 < SEQ) ? (t + 1) : (SEQ - 1);
            FW Bh[2], Bl[2];
#pragma unroll
            for (int kt = 0; kt < 2; ++kt) {
                Bh[kt].q = *(const uint4*)&h0f[cur][0][n][16 * kt + 4 * qg];
                Bl[kt].q = *(const uint4*)&h0f[cur][1][n][16 * kt + 4 * qg];
            }
            f32x4 z = {0.f, 0.f, 0.f, 0.f};
            f32x4 acc[4] = {z, z, z, z};
#pragma unroll
            for (int kt = 0; kt < 2; ++kt)
#pragma unroll
                for (int g = 0; g < 4; ++g) {
                    acc[g] = __builtin_amdgcn_mfma_f32_16x16x32_bf16(Ah[g][kt], Bh[kt].v, acc[g], 0, 0, 0);
                    acc[g] = __builtin_amdgcn_mfma_f32_16x16x32_bf16(Ah[g][kt], Bl[kt].v, acc[g], 0, 0, 0);
                    acc[g] = __builtin_amdgcn_mfma_f32_16x16x32_bf16(Al[g][kt], Bh[kt].v, acc[g], 0, 0, 0);
                }
            // elementwise: gates0(t+1) -> h0(t+1)
            float xv = xs[bb][tx];
            float h[4];
#pragma unroll
            for (int r = 0; r < 4; ++r) {
                float ig = sigf(acc[0][r] + fmaf(xv, wih[0][r], bia[0][r]));
                float fg = sigf(acc[1][r] + fmaf(xv, wih[1][r], bia[1][r]));
                float gg = tanhf_fast(acc[2][r] + fmaf(xv, wih[2][r], bia[2][r]));
                float og = sigf(acc[3][r] + fmaf(xv, wih[3][r], bia[3][r]));
                c0[r] = fg * c0[r] + ig * gg;
                h[r]  = og * tanhf_fast(c0[r]);
            }
            if (act) {
                uint2 hw = {packbf2(h[0], h[1]), packbf2(h[2], h[3])};
                uint2 lw = {packbf2(h[0] - trunc_bf(h[0]), h[1] - trunc_bf(h[1])),
                            packbf2(h[2] - trunc_bf(h[2]), h[3] - trunc_bf(h[3]))};
                *(uint2*)&h0f[nxt][0][n][k2] = hw;
                *(uint2*)&h0f[nxt][1][n][k2] = lw;
            }
            __syncthreads();
        }
    } else {
        // ================= layer 1 waves =================
        const int w = wid - 4;
        bf16x8 Ah[4][4], Al[4][4];           // 4 gate-tiles x 4 k-tiles (K=128)
#pragma unroll
        for (int g = 0; g < 4; ++g) {
            const int row = 64 * g + 16 * w + n;
#pragma unroll
            for (int kt = 0; kt < 4; ++kt) {
                const float* src = (kt < 2) ? &w_ih1[row * HID + 32 * kt + 8 * qg]
                                            : &w_hh1[row * HID + 32 * (kt - 2) + 8 * qg];
                float f[8];
                *(float4*)&f[0] = *(const float4*)src;
                *(float4*)&f[4] = *(const float4*)(src + 4);
                split8(f, Ah[g][kt], Al[g][kt]);
            }
        }
        float bia[4][4];
#pragma unroll
        for (int g = 0; g < 4; ++g)
#pragma unroll
            for (int r = 0; r < 4; ++r) {
                int row = 64 * g + 16 * w + 4 * qg + r;
                bia[g][r] = b_ih1[row] + b_hh1[row];
            }
        const bool act = (n < BT);
        const int  u0  = 16 * w + 4 * qg;
        const int  k2  = u0 >> 1;
        float c1[4] = {0.f, 0.f, 0.f, 0.f};

        __syncthreads();   // pairs with layer0's post-prologue barrier

        for (int t = 0; t < SEQ; ++t) {
            const int cur = t & 1, nxt = cur ^ 1;
            FW Bh[4], Bl[4];
#pragma unroll
            for (int kt = 0; kt < 2; ++kt) {
                Bh[kt].q     = *(const uint4*)&h0f[cur][0][n][16 * kt + 4 * qg];
                Bl[kt].q     = *(const uint4*)&h0f[cur][1][n][16 * kt + 4 * qg];
                Bh[kt + 2].q = *(const uint4*)&h1f[cur][0][n][16 * kt + 4 * qg];
                Bl[kt + 2].q = *(const uint4*)&h1f[cur][1][n][16 * kt + 4 * qg];
            }
            f32x4 z = {0.f, 0.f, 0.f, 0.f};
            f32x4 acc[4] = {z, z, z, z};
#pragma unroll
            for (int kt = 0; kt < 4; ++kt)
#pragma unroll
                for (int g = 0; g < 4; ++g) {
                    acc[g] = __builtin_amdgcn_mfma_f32_16x16x32_bf16(Ah[g][kt], Bh[kt].v, acc[g], 0, 0, 0);
                    acc[g] = __builtin_amdgcn_mfma_f32_16x16x32_bf16(Ah[g][kt], Bl[kt].v, acc[g], 0, 0, 0);
                    acc[g] = __builtin_amdgcn_mfma_f32_16x16x32_bf16(Al[g][kt], Bh[kt].v, acc[g], 0, 0, 0);
                }
            // elementwise: gates1(t) -> h1(t)
            float h[4];
#pragma unroll
            for (int r = 0; r < 4; ++r) {
                float ig = sigf(acc[0][r] + bia[0][r]);
                float fg = sigf(acc[1][r] + bia[1][r]);
                float gg = tanhf_fast(acc[2][r] + bia[2][r]);
                float og = sigf(acc[3][r] + bia[3][r]);
                c1[r] = fg * c1[r] + ig * gg;
                h[r]  = og * tanhf_fast(c1[r]);
            }
            if (act) {
                uint2 hw = {packbf2(h[0], h[1]), packbf2(h[2], h[3])};
                uint2 lw = {packbf2(h[0] - trunc_bf(h[0]), h[1] - trunc_bf(h[1])),
                            packbf2(h[2] - trunc_bf(h[2]), h[3] - trunc_bf(h[3]))};
                *(uint2*)&h1f[nxt][0][n][k2] = hw;
                *(uint2*)&h1f[nxt][1][n][k2] = lw;
                *(float4*)&h1last[n][u0] = float4{h[0], h[1], h[2], h[3]};
            }
            __syncthreads();
        }
    }

    // ===== final projection: out[b][o] = fc_b[o] + h1(511) . fc_w[o] =====
    if (tid < BT * NOUT) {
        int b = tid / NOUT, o = tid % NOUT;
        float acc = fc_b[o];
#pragma unroll
        for (int j = 0; j < HID; ++j)
            acc = fmaf(fc_w[o * HID + j], h1last[b][j], acc);
        out[(size_t)(b0 + b) * NOUT + o] = acc;
    }
}

extern "C" void kernel_launch(void* const* d_in, const int* in_sizes, int n_in,
                              void* d_out, int out_size, void* d_ws, size_t ws_size,
                              hipStream_t stream) {
    const float* x     = (const float*)d_in[0];
    const float* w_ih0 = (const float*)d_in[1];
    const float* w_hh0 = (const float*)d_in[2];
    const float* b_ih0 = (const float*)d_in[3];
    const float* b_hh0 = (const float*)d_in[4];
    const float* w_ih1 = (const float*)d_in[5];
    const float* w_hh1 = (const float*)d_in[6];
    const float* b_ih1 = (const float*)d_in[7];
    const float* b_hh1 = (const float*)d_in[8];
    const float* fc_w  = (const float*)d_in[9];
    const float* fc_b  = (const float*)d_in[10];

    const int B = in_sizes[0] / SEQ;          // 2048
    dim3 grid(B / BT);                        // 256 blocks -> 1 block/CU, 2 waves/SIMD
    lstm2_fused<<<grid, 512, 0, stream>>>(x, w_ih0, w_hh0, b_ih0, b_hh0,
                                          w_ih1, w_hh1, b_ih1, b_hh1,
                                          fc_w, fc_b, (float*)d_out);
}

// Round 8
// 870.351 us; speedup vs baseline: 11.1462x; 1.1908x over previous
//
#include <hip/hip_runtime.h>

#define BT    8      // batch tile per block
#define HID   64
#define SEQ   512
#define NOUT  12
#define KP2   36     // frag row stride in dwords (16B-aligned)
#define GRS   9      // gate-row stride in floats (8 batches + 1 pad)

typedef float  f32x4  __attribute__((ext_vector_type(4)));
typedef short  bf16x8 __attribute__((ext_vector_type(8)));
typedef unsigned int u32;

union FW { bf16x8 v; u32 w[4]; uint4 q; };

__device__ __forceinline__ float sigf(float x)       { return 1.f / (1.f + __expf(-x)); }
__device__ __forceinline__ float tanhf_fast(float x) { return 1.f - 2.f / (1.f + __expf(2.f * x)); }
__device__ __forceinline__ u32  packbf2(float a, float b) {
    return (__float_as_uint(a) >> 16) | (__float_as_uint(b) & 0xFFFF0000u);
}
__device__ __forceinline__ float trunc_bf(float a) {
    return __uint_as_float(__float_as_uint(a) & 0xFFFF0000u);
}
// Split 8 consecutive f32 into hi/lo bf16x8 fragments (element j <-> k-offset j).
__device__ __forceinline__ void split8(const float* src, bf16x8& hi, bf16x8& lo) {
    float f[8];
    *(float4*)&f[0] = *(const float4*)src;
    *(float4*)&f[4] = *(const float4*)(src + 4);
    FW H, L;
#pragma unroll
    for (int i = 0; i < 4; ++i) {
        float a = f[2*i], b = f[2*i+1];
        H.w[i] = packbf2(a, b);
        L.w[i] = packbf2(a - trunc_bf(a), b - trunc_bf(b));
    }
    hi = H.v; lo = L.v;
}

#define MFMA(A, B, C) __builtin_amdgcn_mfma_f32_16x16x32_bf16((A), (B), (C), 0, 0, 0)

// 16 balanced waves (1024 thr), 1 block/CU, 4 waves/SIMD. Wave w computes the
// 16-row band [16w,16w+16) of BOTH layer GEMMs (18 MFMA, split-bf16 3-term).
// Gates round-trip through a conflict-free LDS array; ew phase maps the 1024
// threads onto the 1024 (layer,batch,unit) triples, c-state in registers.
// h exchanged as pre-packed bf16 hi/lo fragment dwords (round-7-proven layout).
__global__ void __launch_bounds__(1024)
lstm2_fused(
    const float* __restrict__ x,      // [B, SEQ, 1]
    const float* __restrict__ w_ih0,  // [256, 1]
    const float* __restrict__ w_hh0,  // [256, 64]
    const float* __restrict__ b_ih0,  // [256]
    const float* __restrict__ b_hh0,  // [256]
    const float* __restrict__ w_ih1,  // [256, 64]
    const float* __restrict__ w_hh1,  // [256, 64]
    const float* __restrict__ b_ih1,  // [256]
    const float* __restrict__ b_hh1,  // [256]
    const float* __restrict__ fc_w,   // [12, 64]
    const float* __restrict__ fc_b,   // [12]
    float* __restrict__ out)          // [B, 12]
{
    __shared__ float xs[BT][SEQ];          // 16 KB
    __shared__ u32   h0f[2][2][16][KP2];   // 9 KB  [dbuf][hi/lo][n][dword]
    __shared__ u32   h1f[2][2][16][KP2];   // 9 KB
    __shared__ float gl[2][256][GRS];      // 18 KB [layer][gate-row][batch]
    __shared__ float h1last[BT][HID + 4];  // 2.1 KB

    const int tid  = threadIdx.x;
    const int wid  = tid >> 6;        // row-tile band (0..15)
    const int lane = tid & 63;
    const int n    = lane & 15;       // MFMA A-row / B-col lane index
    const int qg   = lane >> 4;       // lane k-group (0..3)
    const int b0   = blockIdx.x * BT;

    // ew role: thread <-> (layer, batch, unit)
    const int el = tid >> 9;          // 0..1
    const int eb = (tid >> 6) & 7;    // 0..7
    const int eu = tid & 63;          // 0..63

    // ---- A fragments: 12 x bf16x8 = 48 regs (AGPR-resident, loop-invariant) ----
    const int arow = 16 * wid + n;
    bf16x8 A0h[2], A0l[2], AIh[2], AIl[2], AHh[2], AHl[2];
#pragma unroll
    for (int kt = 0; kt < 2; ++kt) {
        split8(&w_hh0[arow * HID + 32*kt + 8*qg], A0h[kt], A0l[kt]);
        split8(&w_ih1[arow * HID + 32*kt + 8*qg], AIh[kt], AIl[kt]);
        split8(&w_hh1[arow * HID + 32*kt + 8*qg], AHh[kt], AHl[kt]);
    }

    // ---- ew constants: unified formula, wihq=0 for layer 1 ----
    float biasq[4], wihq[4];
#pragma unroll
    for (int q = 0; q < 4; ++q) {
        int row = eu + 64 * q;
        if (el == 0) { biasq[q] = b_ih0[row] + b_hh0[row]; wihq[q] = w_ih0[row]; }
        else         { biasq[q] = b_ih1[row] + b_hh1[row]; wihq[q] = 0.f; }
    }

    // ---- stage x; zero frag buffers (rows n=8..15 stay zero forever) ----
    for (int i = tid; i < BT * SEQ; i += 1024) {
        int b = i >> 9, t = i & (SEQ - 1);
        xs[b][t] = x[(size_t)(b0 + b) * SEQ + t];
    }
    for (int i = tid; i < 2 * 2 * 16 * KP2; i += 1024) {
        ((u32*)h0f)[i] = 0u;
        ((u32*)h1f)[i] = 0u;
    }
    float c = 0.f, h = 0.f;
    __syncthreads();

    // ===== prologue: h0(0) from x(0) only (h0(-1)=0); h1(-1)=0 already =====
    if (el == 0) {
        float xv = xs[eb][0];
        float ig = sigf(fmaf(xv, wihq[0], biasq[0]));
        float gg = tanhf_fast(fmaf(xv, wihq[2], biasq[2]));
        float og = sigf(fmaf(xv, wihq[3], biasq[3]));
        c = ig * gg;
        h = og * tanhf_fast(c);
        float hp = __int_as_float(__builtin_amdgcn_mov_dpp(__float_as_int(h), 0xB1, 0xF, 0xF, true));
        float he = (eu & 1) ? hp : h;
        float ho = (eu & 1) ? h  : hp;
        if (!(eu & 1)) {
            int d = eu >> 1;
            h0f[0][0][eb][d] = packbf2(he, ho);
            h0f[0][1][eb][d] = packbf2(he - trunc_bf(he), ho - trunc_bf(ho));
        }
    }
    __syncthreads();

    for (int t = 0; t < SEQ; ++t) {
        const int cur = t & 1, nxt = cur ^ 1;
        const int tx  = (t + 1 < SEQ) ? (t + 1) : (SEQ - 1);  // clamped dummy at t=511

        // ===== compute: acc0 = W_hh0.h0(t) ; acc1 = W_ih1.h0(t) + W_hh1.h1(t-1)
        f32x4 z = {0.f, 0.f, 0.f, 0.f};
        f32x4 acc0 = z, acc1 = z;
        {
            FW Bh[2], Bl[2];
#pragma unroll
            for (int kt = 0; kt < 2; ++kt) {
                Bh[kt].q = *(const uint4*)&h0f[cur][0][n][16*kt + 4*qg];
                Bl[kt].q = *(const uint4*)&h0f[cur][1][n][16*kt + 4*qg];
            }
#pragma unroll
            for (int kt = 0; kt < 2; ++kt) {
                acc0 = MFMA(A0h[kt], Bh[kt].v, acc0);
                acc0 = MFMA(A0h[kt], Bl[kt].v, acc0);
                acc0 = MFMA(A0l[kt], Bh[kt].v, acc0);
                acc1 = MFMA(AIh[kt], Bh[kt].v, acc1);
                acc1 = MFMA(AIh[kt], Bl[kt].v, acc1);
                acc1 = MFMA(AIl[kt], Bh[kt].v, acc1);
            }
            // reuse the same B registers for h1 fragments
#pragma unroll
            for (int kt = 0; kt < 2; ++kt) {
                Bh[kt].q = *(const uint4*)&h1f[cur][0][n][16*kt + 4*qg];
                Bl[kt].q = *(const uint4*)&h1f[cur][1][n][16*kt + 4*qg];
            }
#pragma unroll
            for (int kt = 0; kt < 2; ++kt) {
                acc1 = MFMA(AHh[kt], Bh[kt].v, acc1);
                acc1 = MFMA(AHh[kt], Bl[kt].v, acc1);
                acc1 = MFMA(AHl[kt], Bh[kt].v, acc1);
            }
        }
        // store gate pre-activations (C/D: col=n, tile-row=4qg+r); <=2-way banks
        if (n < BT) {
#pragma unroll
            for (int r = 0; r < 4; ++r) {
                gl[0][16*wid + 4*qg + r][n] = acc0[r];
                gl[1][16*wid + 4*qg + r][n] = acc1[r];
            }
        }
        __syncthreads();

        // ===== ew: this thread retires (el, eb, eu) =====
        {
            float xv = xs[eb][tx];
            float g0 = gl[el][eu      ][eb];
            float g1 = gl[el][eu +  64][eb];
            float g2 = gl[el][eu + 128][eb];
            float g3 = gl[el][eu + 192][eb];
            float ig = sigf(g0 + fmaf(xv, wihq[0], biasq[0]));
            float fg = sigf(g1 + fmaf(xv, wihq[1], biasq[1]));
            float gg = tanhf_fast(g2 + fmaf(xv, wihq[2], biasq[2]));
            float og = sigf(g3 + fmaf(xv, wihq[3], biasq[3]));
            c = fg * c + ig * gg;
            h = og * tanhf_fast(c);
            // pack (h, partner-h) into bf16 hi/lo words; even-unit lanes store
            float hp = __int_as_float(__builtin_amdgcn_mov_dpp(__float_as_int(h), 0xB1, 0xF, 0xF, true));
            float he = (eu & 1) ? hp : h;
            float ho = (eu & 1) ? h  : hp;
            if (!(eu & 1)) {
                int d = eu >> 1;
                if (el == 0) {
                    h0f[nxt][0][eb][d] = packbf2(he, ho);
                    h0f[nxt][1][eb][d] = packbf2(he - trunc_bf(he), ho - trunc_bf(ho));
                } else {
                    h1f[nxt][0][eb][d] = packbf2(he, ho);
                    h1f[nxt][1][eb][d] = packbf2(he - trunc_bf(he), ho - trunc_bf(ho));
                }
            }
        }
        __syncthreads();
    }

    // layer-1 ew threads still hold h1(511) in register
    if (el == 1) h1last[eb][eu] = h;
    __syncthreads();

    // ===== final projection: out[b][o] = fc_b[o] + h1(511) . fc_w[o] =====
    if (tid < BT * NOUT) {
        int b = tid / NOUT, o = tid % NOUT;
        float acc = fc_b[o];
#pragma unroll
        for (int j = 0; j < HID; ++j)
            acc = fmaf(fc_w[o * HID + j], h1last[b][j], acc);
        out[(size_t)(b0 + b) * NOUT + o] = acc;
    }
}

extern "C" void kernel_launch(void* const* d_in, const int* in_sizes, int n_in,
                              void* d_out, int out_size, void* d_ws, size_t ws_size,
                              hipStream_t stream) {
    const float* x     = (const float*)d_in[0];
    const float* w_ih0 = (const float*)d_in[1];
    const float* w_hh0 = (const float*)d_in[2];
    const float* b_ih0 = (const float*)d_in[3];
    const float* b_hh0 = (const float*)d_in[4];
    const float* w_ih1 = (const float*)d_in[5];
    const float* w_hh1 = (const float*)d_in[6];
    const float* b_ih1 = (const float*)d_in[7];
    const float* b_hh1 = (const float*)d_in[8];
    const float* fc_w  = (const float*)d_in[9];
    const float* fc_b  = (const float*)d_in[10];

    const int B = in_sizes[0] / SEQ;          // 2048
    dim3 grid(B / BT);                        // 256 blocks -> 1 block/CU, 16 waves
    lstm2_fused<<<grid, 1024, 0, stream>>>(x, w_ih0, w_hh0, b_ih0, b_hh0,
                                           w_ih1, w_hh1, b_ih1, b_hh1,
                                           fc_w, fc_b, (float*)d_out);
}